// Round 10
// baseline (466.143 us; speedup 1.0000x reference)
//
#include <hip/hip_runtime.h>

typedef __attribute__((ext_vector_type(8))) short bf16x8;
typedef __attribute__((ext_vector_type(4))) float f32x4;
typedef __attribute__((ext_vector_type(2))) float f32x2;
typedef __attribute__((ext_vector_type(4))) unsigned int u32x4;

static __device__ __forceinline__ unsigned short f2bf(float f) {
    union { float f; unsigned u; } v; v.f = f;
    return (unsigned short)((v.u + 0x7FFFu + ((v.u >> 16) & 1u)) >> 16);
}

// Wp[ch=4][rs=9][oc=256][cw=32] bf16, value = weight[oc][ch*32+cw][r][s] * wscale
__global__ void prep_weights(const float* __restrict__ w, unsigned short* __restrict__ wp) {
    int t = blockIdx.x * 256 + threadIdx.x;      // 0..294911
    const float wscale = 0.02946278254943948f;   // 1/sqrt(3*3*128)
    int cw = t & 31;
    int oc = (t >> 5) & 255;
    int cr = t >> 13;          // 0..35
    int ch = cr / 9;
    int rs = cr - ch * 9;
    int r  = rs / 3;
    int s  = rs - r * 3;
    int c  = ch * 32 + cw;
    wp[t] = f2bf(w[((oc * 128 + c) * 3 + r) * 3 + s] * wscale);
}

// ============ blur_pre v3: coalesced, planar channel-pair, unified edge col ============
// bm[(n*4+cg)*16+chp][t:257][J:260-stride] u32 = 2 bf16 (ch 2chp, 2chp+1); col 256 = J=256 edge.
// Lane L handles J in {4L..4L+3} (+J=256 for L=63); wave = one chp; block = 4 chp x 16 rows.
__global__ __launch_bounds__(256, 2)
void blur_pre(const float* __restrict__ x, unsigned* __restrict__ bm) {
    const int braw = blockIdx.x;                       // 4096
    const int b = ((braw & 7) << 9) | (braw >> 3);     // XCD-contiguous bands
    const int tband = b & 15;
    const int chpg  = (b >> 4) & 3;
    const int cg    = (b >> 6) & 3;
    const int n     = b >> 8;
    const int wv = threadIdx.x >> 6;
    const int L  = threadIdx.x & 63;
    const int chp = chpg * 4 + wv;
    const float* p0 = x + (size_t)(n * 128 + cg * 32 + 2 * chp) * 65536;
    const float* p1 = p0 + 65536;
    const int t0 = tband * 16;
    const int J0 = 4 * L;
    const bool L0 = (L == 0), L63 = (L == 63);
    const int colA = L0 ? 0 : (J0 - 2);
    const int colB = L63 ? 252 : (J0 + 2);
    unsigned* ob = bm + (size_t)((n * 4 + cg) * 16 + chp) * 66820u;   // 257*260

    float h0[4][4], h1[4][4], e0[4], e1[4];
    #pragma unroll
    for (int i = 0; i < 20; ++i) {
        if (i == 19 && tband != 15) break;   // boundary row owned by next band
        const int xr  = t0 - 2 + i;
        const int xrc = xr < 0 ? 0 : (xr > 255 ? 255 : xr);
        const float rm = (xr == xrc) ? 0.125f : 0.f;
        const float* r0 = p0 + (xrc << 8);
        const float* r1 = p1 + (xrc << 8);
        f32x4 rA0, rB0, rA1, rB1;
        __builtin_memcpy(&rA0, r0 + colA, 16);
        __builtin_memcpy(&rB0, r0 + colB, 16);
        __builtin_memcpy(&rA1, r1 + colA, 16);
        __builtin_memcpy(&rB1, r1 + colB, 16);
        // lane-0 / lane-63 window fix-up (branchless)
        const float A0x = L0 ? 0.f : rA0.x, A0y = L0 ? 0.f : rA0.y;
        const float A0z = L0 ? rA0.x : rA0.z, A0w = L0 ? rA0.y : rA0.w;
        const float A1x = L0 ? 0.f : rA1.x, A1y = L0 ? 0.f : rA1.y;
        const float A1z = L0 ? rA1.x : rA1.z, A1w = L0 ? rA1.y : rA1.w;
        const float B0x = L63 ? rB0.z : rB0.x, B0y = L63 ? rB0.w : rB0.y;
        const float B0z = L63 ? 0.f : rB0.z;
        const float B1x = L63 ? rB1.z : rB1.x, B1y = L63 ? rB1.w : rB1.y;
        const float B1z = L63 ? 0.f : rB1.z;
        h0[0][i & 3] = (A0x + 3.f * (A0y + A0z) + A0w) * rm;
        h0[1][i & 3] = (A0y + 3.f * (A0z + A0w) + B0x) * rm;
        h0[2][i & 3] = (A0z + 3.f * (A0w + B0x) + B0y) * rm;
        h0[3][i & 3] = (A0w + 3.f * (B0x + B0y) + B0z) * rm;
        e0[i & 3]    = (B0x + 3.f * B0y) * rm;
        h1[0][i & 3] = (A1x + 3.f * (A1y + A1z) + A1w) * rm;
        h1[1][i & 3] = (A1y + 3.f * (A1z + A1w) + B1x) * rm;
        h1[2][i & 3] = (A1z + 3.f * (A1w + B1x) + B1y) * rm;
        h1[3][i & 3] = (A1w + 3.f * (B1x + B1y) + B1z) * rm;
        e1[i & 3]    = (B1x + 3.f * B1y) * rm;
        if (i >= 3) {
            const int t = t0 + i - 3;
            u32x4 o;
            #pragma unroll
            for (int d = 0; d < 4; ++d) {
                float bv0 = (h0[d][(i-3)&3] + 3.f*(h0[d][(i-2)&3] + h0[d][(i-1)&3]) + h0[d][i&3]) * 0.125f;
                float bv1 = (h1[d][(i-3)&3] + 3.f*(h1[d][(i-2)&3] + h1[d][(i-1)&3]) + h1[d][i&3]) * 0.125f;
                o[d] = (unsigned)f2bf(bv0) | ((unsigned)f2bf(bv1) << 16);
            }
            *(u32x4*)(ob + (size_t)t * 260 + J0) = o;
            if (L63) {
                float c0 = (e0[(i-3)&3] + 3.f*(e0[(i-2)&3] + e0[(i-1)&3]) + e0[i&3]) * 0.125f;
                float c1 = (e1[(i-3)&3] + 3.f*(e1[(i-2)&3] + e1[(i-1)&3]) + e1[i&3]) * 0.125f;
                ob[(size_t)t * 260 + 256] = (unsigned)f2bf(c0) | ((unsigned)f2bf(c1) << 16);
            }
        }
    }
}

// ---------------- stage 2: MFMA conv over blurred (double-buffered LDS) ----------------
#define MF __builtin_amdgcn_mfma_f32_16x16x32_bf16
#define WLOAD(S0, S1, S2, S3, KOFF) {                                          \
    const unsigned short* _wn = wbase + (size_t)(KOFF) * 8192;                 \
    S0 = *(const bf16x8*)(_wn);        S1 = *(const bf16x8*)(_wn + 512);       \
    S2 = *(const bf16x8*)(_wn + 1024); S3 = *(const bf16x8*)(_wn + 1536);      \
}
#define CSTEP(BUF, ADRS, R, S0, S1, S2, S3) {                                  \
    const unsigned char* _ab = lds + (BUF) + (ADRS) + (R) * 2112;              \
    bf16x8 a0 = *(const bf16x8*)(_ab);                                         \
    bf16x8 a1 = *(const bf16x8*)(_ab + 4224);                                  \
    bf16x8 a2 = *(const bf16x8*)(_ab + 8448);                                  \
    bf16x8 a3 = *(const bf16x8*)(_ab + 12672);                                 \
    __builtin_amdgcn_s_setprio(1);                                             \
    acc[0][0]=MF(a0,S0,acc[0][0],0,0,0); acc[0][1]=MF(a0,S1,acc[0][1],0,0,0);  \
    acc[0][2]=MF(a0,S2,acc[0][2],0,0,0); acc[0][3]=MF(a0,S3,acc[0][3],0,0,0);  \
    acc[1][0]=MF(a1,S0,acc[1][0],0,0,0); acc[1][1]=MF(a1,S1,acc[1][1],0,0,0);  \
    acc[1][2]=MF(a1,S2,acc[1][2],0,0,0); acc[1][3]=MF(a1,S3,acc[1][3],0,0,0);  \
    acc[2][0]=MF(a2,S0,acc[2][0],0,0,0); acc[2][1]=MF(a2,S1,acc[2][1],0,0,0);  \
    acc[2][2]=MF(a2,S2,acc[2][2],0,0,0); acc[2][3]=MF(a2,S3,acc[2][3],0,0,0);  \
    acc[3][0]=MF(a3,S0,acc[3][0],0,0,0); acc[3][1]=MF(a3,S1,acc[3][1],0,0,0);  \
    acc[3][2]=MF(a3,S2,acc[3][2],0,0,0); acc[3][3]=MF(a3,S3,acc[3][3],0,0,0);  \
    __builtin_amdgcn_s_setprio(0);                                             \
}
#define CHUNK(BUF, BASE, A0,A1,A2,A3, B0,B1,B2,B3)                             \
    CSTEP(BUF, adr0, 0, A0,A1,A2,A3) WLOAD(A0,A1,A2,A3, (BASE)+2)              \
    CSTEP(BUF, adr1, 0, B0,B1,B2,B3) WLOAD(B0,B1,B2,B3, (BASE)+3)              \
    CSTEP(BUF, adr2, 0, A0,A1,A2,A3) WLOAD(A0,A1,A2,A3, (BASE)+4)              \
    CSTEP(BUF, adr0, 1, B0,B1,B2,B3) WLOAD(B0,B1,B2,B3, (BASE)+5)              \
    CSTEP(BUF, adr1, 1, A0,A1,A2,A3) WLOAD(A0,A1,A2,A3, (BASE)+6)              \
    CSTEP(BUF, adr2, 1, B0,B1,B2,B3) WLOAD(B0,B1,B2,B3, (BASE)+7)              \
    CSTEP(BUF, adr0, 2, A0,A1,A2,A3) WLOAD(A0,A1,A2,A3, (BASE)+8)              \
    CSTEP(BUF, adr1, 2, B0,B1,B2,B3) WLOAD(B0,B1,B2,B3, (BASE)+9)              \
    CSTEP(BUF, adr2, 2, A0,A1,A2,A3) WLOAD(A0,A1,A2,A3, (BASE)+10)
#define CHUNK_LAST(BUF, BASE, A0,A1,A2,A3, B0,B1,B2,B3)                        \
    CSTEP(BUF, adr0, 0, A0,A1,A2,A3) WLOAD(A0,A1,A2,A3, (BASE)+2)              \
    CSTEP(BUF, adr1, 0, B0,B1,B2,B3) WLOAD(B0,B1,B2,B3, (BASE)+3)              \
    CSTEP(BUF, adr2, 0, A0,A1,A2,A3) WLOAD(A0,A1,A2,A3, (BASE)+4)              \
    CSTEP(BUF, adr0, 1, B0,B1,B2,B3) WLOAD(B0,B1,B2,B3, (BASE)+5)              \
    CSTEP(BUF, adr1, 1, A0,A1,A2,A3) WLOAD(A0,A1,A2,A3, (BASE)+6)              \
    CSTEP(BUF, adr2, 1, B0,B1,B2,B3) WLOAD(B0,B1,B2,B3, (BASE)+7)              \
    CSTEP(BUF, adr0, 2, A0,A1,A2,A3) WLOAD(A0,A1,A2,A3, (BASE)+8)              \
    CSTEP(BUF, adr1, 2, B0,B1,B2,B3)                                           \
    CSTEP(BUF, adr2, 2, A0,A1,A2,A3)

__global__ __launch_bounds__(512, 2)
void conv_stage2(const unsigned* __restrict__ bm, const unsigned short* __restrict__ wp,
                 const float* __restrict__ bias, float* __restrict__ out) {
    __shared__ __align__(16) unsigned char lds[2 * 35904];   // dbuf: 17 rows x 33 granules x 64B

    const int bx = blockIdx.x;
    const int n  = bx >> 7;
    const int tt = bx & 127;
    const int u0 = (tt >> 3) * 8;
    const int v0 = (tt & 7) * 16;

    const int tid  = threadIdx.x;
    const int lane = tid & 63;
    const int wid  = tid >> 6;
    const int wm   = wid >> 2;       // 0..1
    const int wn   = wid & 3;        // 0..3
    const int g    = lane >> 4;
    const int wq   = lane & 15;

    // ---- staging geometry: 2448 tasks = (row 17 x chp 16) x Jq 9 ----
    unsigned goffm[5], ldsa[5];
    bool act[5], isq8[5];
    #pragma unroll
    for (int ii = 0; ii < 5; ++ii) {
        int k = tid + 512 * ii;
        act[ii] = (k < 2448);
        int kk = act[ii] ? k : 0;
        int pr = kk / 9;
        int Jq = kk - 9 * pr;
        int chp = pr & 15;
        int row = pr >> 4;
        int t = 2 * u0 + row;
        isq8[ii] = (Jq == 8);
        int col = isq8[ii] ? (2 * v0 + 32) : (2 * v0 + 4 * Jq);   // ==256 at v0=112: edge col
        goffm[ii] = (unsigned)((chp * 257 + t) * 260 + col);
        if (Jq < 8) {
            ldsa[ii] = (unsigned)(row * 2112 + Jq * 256
                     + (((chp >> 2) ^ (Jq & 3)) << 4) + (chp & 3) * 4);
        } else {
            ldsa[ii] = (unsigned)(row * 2112 + 2048 + ((chp >> 2) << 4) + (chp & 3) * 4);
        }
    }
    const unsigned* bmn = bm + (size_t)(n * 4) * 16 * 66820u;
    u32x4 SV[5];

#define STAGE_LOAD(CG) {                                                       \
    const unsigned* _m = bmn + (size_t)(CG) * 16 * 66820u;                     \
    _Pragma("unroll")                                                          \
    for (int ii = 0; ii < 5; ++ii) {                                           \
        if (act[ii]) {                                                         \
            if (!isq8[ii]) { SV[ii] = *(const u32x4*)(_m + goffm[ii]); }       \
            else { SV[ii].x = _m[goffm[ii]]; }                                 \
        }                                                                      \
    }                                                                          \
}
#define STAGE_WRITE(BUF) {                                                     \
    _Pragma("unroll")                                                          \
    for (int ii = 0; ii < 5; ++ii) {                                           \
        if (act[ii]) {                                                         \
            if (!isq8[ii]) {                                                   \
                *(unsigned*)(lds + (BUF) + ldsa[ii])       = SV[ii].x;         \
                *(unsigned*)(lds + (BUF) + ldsa[ii] + 64)  = SV[ii].y;         \
                *(unsigned*)(lds + (BUF) + ldsa[ii] + 192) = SV[ii].z;         \
                *(unsigned*)(lds + (BUF) + ldsa[ii] + 128) = SV[ii].w;         \
            } else {                                                           \
                *(unsigned*)(lds + (BUF) + ldsa[ii]) = SV[ii].x;               \
            }                                                                  \
        }                                                                      \
    }                                                                          \
}

    // A-frag LDS bases (bj = 2wq + s; granule swizzle J^((J>>1)&1), slot g^((J>>2)&3))
    unsigned adr0, adr1, adr2;
    {
        #pragma unroll
        for (int s = 0; s < 3; ++s) {
            unsigned bj = 2u * (unsigned)wq + (unsigned)s;
            unsigned av = (bj ^ ((bj >> 1) & 1u)) * 64u
                        + (((unsigned)g ^ ((bj >> 2) & 3u)) << 4) + (unsigned)wm * 16896u;
            if (s == 0) adr0 = av; else if (s == 1) adr1 = av; else adr2 = av;
        }
    }

    const unsigned short* wbase = wp + (size_t)(wn * 64 + wq) * 32 + g * 8;
    bf16x8 WA0, WA1, WA2, WA3, WB0, WB1, WB2, WB3;
    WLOAD(WA0, WA1, WA2, WA3, 0)
    WLOAD(WB0, WB1, WB2, WB3, 1)

    f32x4 acc[4][4];
    #pragma unroll
    for (int i = 0; i < 4; ++i)
        #pragma unroll
        for (int j = 0; j < 4; ++j)
            acc[i][j] = (f32x4){0.f, 0.f, 0.f, 0.f};

    // prologue: fill buf0, start loads for chunk 1
    STAGE_LOAD(0)
    STAGE_WRITE(0)
    __syncthreads();
    STAGE_LOAD(1)

    CHUNK(0, 0, WA0, WA1, WA2, WA3, WB0, WB1, WB2, WB3)
    STAGE_WRITE(35904)                 // buf1 <- chunk1 (loads flew under CHUNK 0)
    __syncthreads();
    STAGE_LOAD(2)

    CHUNK(35904, 9, WB0, WB1, WB2, WB3, WA0, WA1, WA2, WA3)
    STAGE_WRITE(0)                     // buf0 <- chunk2
    __syncthreads();
    STAGE_LOAD(3)

    CHUNK(0, 18, WA0, WA1, WA2, WA3, WB0, WB1, WB2, WB3)
    STAGE_WRITE(35904)                 // buf1 <- chunk3
    __syncthreads();

    CHUNK_LAST(35904, 27, WB0, WB1, WB2, WB3, WA0, WA1, WA2, WA3)

    // epilogue: u = u0 + wm*4 + mf, v = v0 + 4g + i, oc = wn*64 + nf*16 + wq
    const float gain = 1.4142135623730951f;
    #pragma unroll
    for (int nf = 0; nf < 4; ++nf) {
        const int ocg = wn * 64 + nf * 16 + wq;
        const float bb = bias[ocg];
        #pragma unroll
        for (int mf = 0; mf < 4; ++mf) {
            int u = u0 + wm * 4 + mf;
            f32x4 o;
            #pragma unroll
            for (int i = 0; i < 4; ++i) {
                float z = acc[mf][nf][i] + bb;
                z = (z >= 0.f ? z : 0.2f * z) * gain;
                o[i] = fminf(fmaxf(z, -256.f), 256.f);
            }
            *(f32x4*)(out + (((size_t)n * 256 + ocg) * 128 + u) * 128 + v0 + 4 * g) = o;
        }
    }
}

// ======================= Fallback: proven R5 fused kernel =======================
#define FROW(row) {                                                            \
    int xr  = xr0 + (row);                                                     \
    int xrc = xr < 0 ? 0 : (xr > 255 ? 255 : xr);                              \
    float rm = (xr == xrc) ? 0.125f : 0.0f;                                    \
    const float* p = q + (xrc << 8);                                           \
    f32x4 lo; f32x2 hi;                                                        \
    __builtin_memcpy(&lo, p, 16);                                              \
    __builtin_memcpy(&hi, p + 4, 8);                                           \
    hA[(row) & 3] = (lo.x + 3.f * (lo.y + lo.z) + lo.w) * rm;                  \
    hB[(row) & 3] = (lo.y + 3.f * (lo.z + lo.w) + hi.x) * rm;                  \
    hC[(row) & 3] = (lo.z + 3.f * (lo.w + hi.x) + hi.y) * rm;                  \
}
#define SROW(row) {                                                            \
    int xr = xr0 + (row);                                                      \
    float wv0=0.f,wv1=0.f,wv2=0.f,wv3=0.f,wv4=0.f,wv5=0.f;                     \
    if ((unsigned)xr < 256u) {                                                 \
        const float* p = q + (xr << 8);                                        \
        if ((unsigned)(wc + 0) < 256u) wv0 = p[0];                             \
        if ((unsigned)(wc + 1) < 256u) wv1 = p[1];                             \
        if ((unsigned)(wc + 2) < 256u) wv2 = p[2];                             \
        if ((unsigned)(wc + 3) < 256u) wv3 = p[3];                             \
        if ((unsigned)(wc + 4) < 256u) wv4 = p[4];                             \
        if ((unsigned)(wc + 5) < 256u) wv5 = p[5];                             \
    }                                                                          \
    hA[(row) & 3] = (wv0 + 3.f * (wv1 + wv2) + wv3) * 0.125f;                  \
    hB[(row) & 3] = (wv1 + 3.f * (wv2 + wv3) + wv4) * 0.125f;                  \
    hC[(row) & 3] = (wv2 + 3.f * (wv3 + wv4) + wv5) * 0.125f;                  \
}
#define VROW(row) {                                                            \
    float bv0 = (hA[(row - 3) & 3] + 3.f * (hA[(row - 2) & 3] + hA[(row - 1) & 3]) + hA[(row) & 3]) * 0.125f; \
    float bv1 = (hB[(row - 3) & 3] + 3.f * (hB[(row - 2) & 3] + hB[(row - 1) & 3]) + hB[(row) & 3]) * 0.125f; \
    unsigned rb = (unsigned)(row - 3) * 2640u;                                 \
    *(unsigned short*)(flds + rb + o0) = f2bf(bv0);                            \
    *(unsigned short*)(flds + rb + o1) = f2bf(bv1);                            \
    if (a == 15) {                                                             \
        float bv2 = (hC[(row - 3) & 3] + 3.f * (hC[(row - 2) & 3] + hC[(row - 1) & 3]) + hC[(row) & 3]) * 0.125f; \
        *(unsigned short*)(flds + rb + o2) = f2bf(bv2);                        \
    }                                                                          \
}
__global__ __launch_bounds__(512, 4)
void conv_blur_mfma(const float* __restrict__ x, const unsigned short* __restrict__ wp,
                    const float* __restrict__ bias, float* __restrict__ out) {
    __shared__ __align__(16) unsigned char flds[17 * 33 * 80];
    const int bx = blockIdx.x;
    const int n  = bx >> 7;
    const int tt = bx & 127;
    const int u0 = (tt >> 3) * 8;
    const int v0 = (tt & 7) * 16;
    const int tid  = threadIdx.x;
    const int lane = tid & 63;
    const int wid  = tid >> 6;
    const int wm   = wid >> 2;
    const int wn   = wid & 3;
    const int g    = lane >> 4;
    const int wq   = lane & 15;
    const int a   = tid & 15;
    const int chl = tid >> 4;
    const int wc  = 2 * v0 - 2 + 2 * a;
    const bool edge = (v0 == 0 && a == 0) || (v0 == 112 && a == 15);
    const float* planeBase = x + (size_t)(n * 128 + chl) * 65536;
    const int xr0 = 2 * u0 - 2;
    const unsigned chpart = (unsigned)(((chl >> 1) & 3) * 4 + (chl & 1) * 2);
    const unsigned q4 = (unsigned)(chl >> 3);
    const int c0 = 2 * a;
    const unsigned o0 = (unsigned)(c0 + 0) * 80u + ((q4 ^ (((unsigned)(c0 + 0) >> 3) & 3u)) << 4) + chpart;
    const unsigned o1 = (unsigned)(c0 + 1) * 80u + ((q4 ^ (((unsigned)(c0 + 1) >> 3) & 3u)) << 4) + chpart;
    const unsigned o2 = (unsigned)(c0 + 2) * 80u + ((q4 ^ (((unsigned)(c0 + 2) >> 3) & 3u)) << 4) + chpart;
    const unsigned short* wpL = wp + (size_t)(wn * 64 + wq) * 32 + g * 8;
    f32x4 acc[4][4];
    #pragma unroll
    for (int i = 0; i < 4; ++i)
        #pragma unroll
        for (int j = 0; j < 4; ++j)
            acc[i][j] = (f32x4){0.f, 0.f, 0.f, 0.f};
    for (int ch = 0; ch < 4; ++ch) {
        const float* q = planeBase + (size_t)ch * 32 * 65536 + wc;
        float hA[4], hB[4], hC[4];
        if (!edge) { FROW(0) FROW(1) FROW(2) }
        else       { SROW(0) SROW(1) SROW(2) }
        __syncthreads();
        if (!edge) {
            #pragma unroll
            for (int row = 3; row < 20; ++row) { FROW(row) VROW(row) }
        } else {
            #pragma unroll
            for (int row = 3; row < 20; ++row) { SROW(row) VROW(row) }
        }
        __syncthreads();
        const unsigned short* wpc = wpL + (size_t)ch * 9 * 8192;
        #pragma unroll 1
        for (int r = 0; r < 3; ++r) {
            #pragma unroll 1
            for (int s = 0; s < 3; ++s) {
                bf16x8 b0 = *(const bf16x8*)(wpc + 0 * 512);
                bf16x8 b1 = *(const bf16x8*)(wpc + 1 * 512);
                bf16x8 b2 = *(const bf16x8*)(wpc + 2 * 512);
                bf16x8 b3 = *(const bf16x8*)(wpc + 3 * 512);
                wpc += 8192;
                int bj = 2 * wq + s;
                unsigned cb = (unsigned)bj * 80u + ((unsigned)(g ^ ((bj >> 3) & 3)) << 4);
                #pragma unroll
                for (int mf = 0; mf < 4; ++mf) {
                    int bi = 2 * (wm * 4 + mf) + r;
                    bf16x8 afrag = *(const bf16x8*)(flds + (unsigned)bi * 2640u + cb);
                    acc[mf][0] = MF(afrag, b0, acc[mf][0], 0, 0, 0);
                    acc[mf][1] = MF(afrag, b1, acc[mf][1], 0, 0, 0);
                    acc[mf][2] = MF(afrag, b2, acc[mf][2], 0, 0, 0);
                    acc[mf][3] = MF(afrag, b3, acc[mf][3], 0, 0, 0);
                }
            }
        }
    }
    const float gain = 1.4142135623730951f;
    #pragma unroll
    for (int nf = 0; nf < 4; ++nf) {
        int ocg = wn * 64 + nf * 16 + wq;
        float bv = bias[ocg];
        #pragma unroll
        for (int mf = 0; mf < 4; ++mf) {
            int u = u0 + wm * 4 + mf;
            f32x4 o;
            #pragma unroll
            for (int i = 0; i < 4; ++i) {
                float z = acc[mf][nf][i] + bv;
                z = (z >= 0.f ? z : 0.2f * z) * gain;
                o[i] = fminf(fmaxf(z, -256.f), 256.f);
            }
            *(f32x4*)(out + (((size_t)n * 256 + ocg) * 128 + u) * 128 + v0 + 4 * g) = o;
        }
    }
}

extern "C" void kernel_launch(void* const* d_in, const int* in_sizes, int n_in,
                              void* d_out, int out_size, void* d_ws, size_t ws_size,
                              hipStream_t stream) {
    const float* x    = (const float*)d_in[0];
    const float* w    = (const float*)d_in[1];
    const float* bias = (const float*)d_in[2];
    unsigned short* wp = (unsigned short*)d_ws;           // 589,824 B
    float* out = (float*)d_out;

    const size_t BM_BYTES = (size_t)1024 * 66820 * 4;     // 273,694,720
    const size_t NEED = 589824u + BM_BYTES;
    prep_weights<<<1152, 256, 0, stream>>>(w, wp);
    if (ws_size >= NEED) {
        unsigned* bm = (unsigned*)((unsigned char*)d_ws + 589824);
        blur_pre<<<4096, 256, 0, stream>>>(x, bm);
        conv_stage2<<<2048, 512, 0, stream>>>(bm, wp, bias, out);
    } else {
        conv_blur_mfma<<<2048, 512, 0, stream>>>(x, wp, bias, out);
    }
}